// Round 12
// baseline (455.476 us; speedup 1.0000x reference)
//
#include <hip/hip_runtime.h>
#include <hip/hip_bf16.h>

typedef __bf16 bf16x8 __attribute__((ext_vector_type(8)));
typedef __bf16 bf16x4 __attribute__((ext_vector_type(4)));
typedef float  f32x4  __attribute__((ext_vector_type(4)));

#define LAYERS 16
#define DIM 64
#define NHID 256
#define BATCH 32768
#define MTILE 64
#define NBLOCKS (BATCH / MTILE)   // 512 -> 2 blocks/CU (the proven regime)

// packed weight sizes in bf16 elements
#define W0P_PER 16384             // per (net,layer): 16 otiles * 2 ktiles * 512
#define W1P_PER 65536             // 16 otiles * 8 ktiles * 512
#define W2P_PER 16384             // 4 otiles * 8 ktiles * 512
#define W0P_TOT (32 * W0P_PER)    // 524288
#define W1P_TOT (32 * W1P_PER)    // 2097152
#define W2P_TOT (32 * W2P_PER)    // 524288
#define PACK_TOT (W0P_TOT + W1P_TOT + W2P_TOT)  // 3145728 bf16 = 6.29 MB

__device__ __forceinline__ bf16x8 ldw(const __bf16* p) { return *(const bf16x8*)p; }

// ---------------------------------------------------------------------------
// Pack kernel (unchanged from r7): analytic masks, MFMA fragment layout:
// per (net,layer,gemm): [otile][ktile][lane(64)][j(8)].
// ---------------------------------------------------------------------------
__global__ __launch_bounds__(256) void pack_weights(
    const float* __restrict__ lW0, const float* __restrict__ lW1, const float* __restrict__ lW2,
    const float* __restrict__ sW0, const float* __restrict__ sW1, const float* __restrict__ sW2,
    __bf16* __restrict__ ws)
{
    const long i = ((long)blockIdx.x * 256 + threadIdx.x) * 8;  // elem base
    const float* W; long src; int l, n, k, which;
    if (i < W0P_TOT) {
        int netl = (int)(i / W0P_PER), rem = (int)(i % W0P_PER);
        int net = netl >> 4; l = netl & 15;
        int nt = rem >> 10, kt = (rem >> 9) & 1, lane = (rem >> 3) & 63;
        n = nt * 16 + (lane & 15); k = kt * 32 + (lane >> 4) * 8;
        W = net ? sW0 : lW0; which = 0;
        src = (long)(l * 256 + n) * 64 + k;
    } else if (i < W0P_TOT + W1P_TOT) {
        long r = i - W0P_TOT;
        int netl = (int)(r / W1P_PER), rem = (int)(r % W1P_PER);
        int net = netl >> 4; l = netl & 15;
        int nt = rem >> 12, kt = (rem >> 9) & 7, lane = (rem >> 3) & 63;
        n = nt * 16 + (lane & 15); k = kt * 32 + (lane >> 4) * 8;
        W = net ? sW1 : lW1; which = 1;
        src = (long)(l * 256 + n) * 256 + k;
    } else {
        long r = i - W0P_TOT - W1P_TOT;
        int netl = (int)(r / W2P_PER), rem = (int)(r % W2P_PER);
        int net = netl >> 4; l = netl & 15;
        int nt = rem >> 12, kt = (rem >> 9) & 7, lane = (rem >> 3) & 63;
        n = nt * 16 + (lane & 15); k = kt * 32 + (lane >> 4) * 8;
        W = net ? sW2 : lW2; which = 2;
        src = (long)(l * 64 + n) * 256 + k;
    }
    f32x4 wa = *(const f32x4*)(W + src);
    f32x4 wb = *(const f32x4*)(W + src + 4);
    const int nm = n % 63;                   // mh(n) for which 0/1
    const int pn = (l & 1) ? 63 - n : n;     // perm(n) for which 2 (n < 64 there)
    bf16x8 o;
    #pragma unroll
    for (int j = 0; j < 8; ++j) {
        int kk = k + j;
        bool m;
        if (which == 0)      { int pk = (l & 1) ? 63 - kk : kk; m = (pk <= nm); }
        else if (which == 1) { m = ((kk % 63) <= nm); }
        else                 { m = ((kk % 63) < pn); }
        float v = (j < 4) ? wa[j] : wb[j - 4];
        o[j] = m ? (__bf16)v : (__bf16)0.0f;
    }
    *(bf16x8*)(ws + i) = o;
}

// ---------------------------------------------------------------------------
// Flow kernel, round 12: FUSED loc+scale chain. The two nets are independent
// given y, so their GEMMs merge into one otile space (0-15 loc, 16-31 scale):
// phases/layer drop 8 -> 4 (64 total), each with 2x MFMA. MTILE 64, 512 thr
// (8 waves), in-place h1 over h0 in ONE fused 64 KB buffer -> LDS 72 KB ->
// 2 blocks/CU preserved (r9/r11 proved 2 co-resident blocks are load-bearing).
// __launch_bounds__(512,2): the honored form (r11 granted 104).
// Wave maps:
//   G1/G2: net12=wave>>2 (uniform per wave), local otiles lob..lob+3 where
//          lob=(wave&3)*4; fused otile o = net12*16 + lob + ot; all 4 bt.
//   G3/y/coupling: dt=wave>>1 (dim tile), bts {2(wave&1), 2(wave&1)+1};
//          computes BOTH nets -> coupling is pure in-lane register math.
// buf layout: [bt(4)][ktf(16)][lane][8]; h0/h1 fused hidden hf = net*256+h,
// ktf = o>>1 with o = fused otile; net n's slice = ktf n*8..n*8+7.
// Barriers: B1 (ybf ready + prev G3 reads done), B2 (h0 ready),
//           B3 (h0 reads done; write h1 in place), B4 (h1 ready).
// Prefetch (r9-proven scale): wg1[8] (next G1, in G3), wg2a[4] (G2 kt0,
// in G1), wg3[4] (G3 loc/sc kt0-1, in G2).
// ---------------------------------------------------------------------------
__global__ void __launch_bounds__(512, 2)
flow_kernel(
    const float* __restrict__ u,
    const __bf16* __restrict__ wp,
    const float* __restrict__ lb0, const float* __restrict__ lb1, const float* __restrict__ lb2,
    const float* __restrict__ sb0, const float* __restrict__ sb1, const float* __restrict__ sb2,
    float* __restrict__ out)
{
    __shared__ __bf16 ybf[4 * 2 * 512];    // [bt(4)][kt(2)][lane][8]    8 KB
    __shared__ __bf16 buf[4 * 16 * 512];   // [bt(4)][ktf(16)][lane][8] 64 KB

    const int tid  = threadIdx.x;
    const int wave = tid >> 6;        // 0..7
    const int lane = tid & 63;
    const int quad = lane >> 4;
    const int l16  = lane & 15;
    const int blk  = blockIdx.x;

    const int qh = quad >> 1;         // epilogue frag-lane sub-index
    const int qp = (quad & 1) * 4;    // epilogue j base

    const int net12 = wave >> 2;      // G1/G2: wave's net (0=loc, 1=scale)
    const int lob   = (wave & 3) * 4; // local otile base within net

    const int dt  = wave >> 1;        // G3/y: dim tile (0..3)
    const int hb2 = (wave & 1) * 2;   // G3/y: batch-tile base (0 or 2)

    const __bf16* w0p = wp;
    const __bf16* w1p = wp + W0P_TOT;
    const __bf16* w2p = wp + W0P_TOT + W1P_TOT;

    // y regs (D-layout): y[j][r] = row (blk*64 + (hb2+j)*16 + l16), dim (dt*16 + quad*4 + r)
    f32x4 y[2];
    #pragma unroll
    for (int j = 0; j < 2; ++j)
        y[j] = *(const f32x4*)(u + (long)(blk * MTILE + (hb2 + j) * 16 + l16) * DIM
                                 + dt * 16 + quad * 4);

    // y-staging fragment coords for dim chunk [dt*16, dt*16+16)
    const int ktY = dt >> 1;
    const int flY = ((dt & 1) * 2 + qh) * 16 + l16;

    // prime: G1 weights (net12, layer 0), local otiles lob..lob+3
    bf16x8 wg1[8];   // [ot][kt]
    #pragma unroll
    for (int ot = 0; ot < 4; ++ot)
        #pragma unroll
        for (int kt = 0; kt < 2; ++kt)
            wg1[ot * 2 + kt] = ldw(w0p + (long)(net12 * 16) * W0P_PER
                                       + (long)((lob + ot) * 2 + kt) * 512 + lane * 8);

    for (int l = 0; l < LAYERS; ++l) {
        // stage y -> bf16 B-fragments (one b64 write per owned bt)
        #pragma unroll
        for (int j = 0; j < 2; ++j) {
            bf16x4 v;
            #pragma unroll
            for (int r = 0; r < 4; ++r) v[r] = (__bf16)y[j][r];
            *(bf16x4*)&ybf[(((hb2 + j) * 2 + ktY) * 64 + flY) * 8 + qp] = v;
        }
        __syncthreads();  // B1: ybf ready; prev layer's G3 buf reads all done

        const __bf16* w1b = w1p + (long)(net12 * 16 + l) * W1P_PER;
        const __bf16* w2l = w2p + (long)l * W2P_PER;            // loc W2
        const __bf16* w2s = w2p + (long)(16 + l) * W2P_PER;     // scale W2
        const float*  b0  = (net12 ? sb0 : lb0) + l * 256;
        const float*  b1  = (net12 ? sb1 : lb1) + l * 256;

        bf16x8 wg2a[4];   // G2 weights kt0 x ot 0..3

        // ---- G1 (fused): W0[net12] (A, prefetched) x y (B=ybf) -> h0 frags
        {
            f32x4 acc[4][4];
            #pragma unroll
            for (int ot = 0; ot < 4; ++ot)
                #pragma unroll
                for (int bt = 0; bt < 4; ++bt)
                    acc[ot][bt] = (f32x4){0.f, 0.f, 0.f, 0.f};
            #pragma unroll
            for (int kt = 0; kt < 2; ++kt) {
                bf16x8 bv[4];
                #pragma unroll
                for (int bt = 0; bt < 4; ++bt)
                    bv[bt] = *(const bf16x8*)&ybf[((bt * 2 + kt) * 64 + lane) * 8];
                #pragma unroll
                for (int ot = 0; ot < 4; ++ot)
                    #pragma unroll
                    for (int bt = 0; bt < 4; ++bt)
                        acc[ot][bt] = __builtin_amdgcn_mfma_f32_16x16x32_bf16(wg1[ot * 2 + kt], bv[bt], acc[ot][bt], 0, 0, 0);
            }
            // prefetch G2 kt=0 across the upcoming barrier
            #pragma unroll
            for (int ot = 0; ot < 4; ++ot)
                wg2a[ot] = ldw(w1b + (long)((lob + ot) * 8) * 512 + lane * 8);
            // epilogue: relu + bias -> buf (h0 fragments; overwrites prev h1, safe past B1)
            #pragma unroll
            for (int ot = 0; ot < 4; ++ot) {
                const int o = net12 * 16 + lob + ot;   // fused otile 0..31
                f32x4 bias = *(const f32x4*)(b0 + (lob + ot) * 16 + quad * 4);
                const int ktf = o >> 1;
                const int fl  = ((o & 1) * 2 + qh) * 16 + l16;
                #pragma unroll
                for (int bt = 0; bt < 4; ++bt) {
                    bf16x4 v;
                    #pragma unroll
                    for (int r = 0; r < 4; ++r)
                        v[r] = (__bf16)fmaxf(acc[ot][bt][r] + bias[r], 0.f);
                    *(bf16x4*)&buf[((bt * 16 + ktf) * 64 + fl) * 8 + qp] = v;
                }
            }
        }
        __syncthreads();  // B2: h0 (both nets) ready

        bf16x8 wg3[4];    // G3 weights: loc kt0-1, scale kt0-1
        bf16x4 hv[4][4];  // packed h1 values held across B3 (32 VGPR)

        // ---- G2 (fused): W1[net12] (A) x h0[net12 slice] (B=buf) -> hv
        {
            f32x4 acc2[4][4];
            #pragma unroll
            for (int ot = 0; ot < 4; ++ot)
                #pragma unroll
                for (int bt = 0; bt < 4; ++bt)
                    acc2[ot][bt] = (f32x4){0.f, 0.f, 0.f, 0.f};
            #pragma unroll
            for (int kt = 0; kt < 8; ++kt) {
                bf16x8 aw[4];
                #pragma unroll
                for (int ot = 0; ot < 4; ++ot)
                    aw[ot] = (kt < 1) ? wg2a[ot]
                                      : ldw(w1b + (long)((lob + ot) * 8 + kt) * 512 + lane * 8);
                bf16x8 bv[4];
                #pragma unroll
                for (int bt = 0; bt < 4; ++bt)
                    bv[bt] = *(const bf16x8*)&buf[((bt * 16 + net12 * 8 + kt) * 64 + lane) * 8];
                #pragma unroll
                for (int ot = 0; ot < 4; ++ot)
                    #pragma unroll
                    for (int bt = 0; bt < 4; ++bt)
                        acc2[ot][bt] = __builtin_amdgcn_mfma_f32_16x16x32_bf16(aw[ot], bv[bt], acc2[ot][bt], 0, 0, 0);
            }
            // fold bias+relu+cvt so only packed bf16 crosses B3
            #pragma unroll
            for (int ot = 0; ot < 4; ++ot) {
                f32x4 bias = *(const f32x4*)(b1 + (lob + ot) * 16 + quad * 4);
                #pragma unroll
                for (int bt = 0; bt < 4; ++bt)
                    #pragma unroll
                    for (int r = 0; r < 4; ++r)
                        hv[ot][bt][r] = (__bf16)fmaxf(acc2[ot][bt][r] + bias[r], 0.f);
            }
            // prefetch G3 kt0-1 for both nets across B3/B4
            #pragma unroll
            for (int kt = 0; kt < 2; ++kt) {
                wg3[kt]     = ldw(w2l + (long)(dt * 8 + kt) * 512 + lane * 8);
                wg3[2 + kt] = ldw(w2s + (long)(dt * 8 + kt) * 512 + lane * 8);
            }
        }
        __syncthreads();  // B3: all h0 reads done — buf may be overwritten

        // ---- write h1 fragments IN PLACE
        #pragma unroll
        for (int ot = 0; ot < 4; ++ot) {
            const int o = net12 * 16 + lob + ot;
            const int ktf = o >> 1;
            const int fl  = ((o & 1) * 2 + qh) * 16 + l16;
            #pragma unroll
            for (int bt = 0; bt < 4; ++bt)
                *(bf16x4*)&buf[((bt * 16 + ktf) * 64 + fl) * 8 + qp] = hv[ot][bt];
        }
        __syncthreads();  // B4: h1 (both nets) ready

        // ---- G3 (fused): both nets' W2 x h1 slices -> loc & scale in-lane
        {
            f32x4 accL[2], accS[2];
            #pragma unroll
            for (int j = 0; j < 2; ++j) {
                accL[j] = (f32x4){0.f, 0.f, 0.f, 0.f};
                accS[j] = (f32x4){0.f, 0.f, 0.f, 0.f};
            }
            #pragma unroll
            for (int kt = 0; kt < 8; ++kt) {
                bf16x8 awL = (kt < 2) ? wg3[kt]
                                      : ldw(w2l + (long)(dt * 8 + kt) * 512 + lane * 8);
                bf16x8 awS = (kt < 2) ? wg3[2 + kt]
                                      : ldw(w2s + (long)(dt * 8 + kt) * 512 + lane * 8);
                #pragma unroll
                for (int j = 0; j < 2; ++j) {
                    bf16x8 bvL = *(const bf16x8*)&buf[(((hb2 + j) * 16 + kt) * 64 + lane) * 8];
                    bf16x8 bvS = *(const bf16x8*)&buf[(((hb2 + j) * 16 + 8 + kt) * 64 + lane) * 8];
                    accL[j] = __builtin_amdgcn_mfma_f32_16x16x32_bf16(awL, bvL, accL[j], 0, 0, 0);
                    accS[j] = __builtin_amdgcn_mfma_f32_16x16x32_bf16(awS, bvS, accS[j], 0, 0, 0);
                }
            }
            // prefetch next layer's G1 weights (low-pressure region).
            // (l+1)&15 keeps the address in-bounds; values unused at l=15.
            const __bf16* w0n = w0p + (long)(net12 * 16 + ((l + 1) & 15)) * W0P_PER;
            #pragma unroll
            for (int ot = 0; ot < 4; ++ot)
                #pragma unroll
                for (int kt = 0; kt < 2; ++kt)
                    wg1[ot * 2 + kt] = ldw(w0n + (long)((lob + ot) * 2 + kt) * 512 + lane * 8);
            // bias + coupling, pure registers: y = exp(-sc) * (y - loc)
            f32x4 biasL = *(const f32x4*)(lb2 + l * 64 + dt * 16 + quad * 4);
            f32x4 biasS = *(const f32x4*)(sb2 + l * 64 + dt * 16 + quad * 4);
            #pragma unroll
            for (int j = 0; j < 2; ++j)
                #pragma unroll
                for (int r = 0; r < 4; ++r) {
                    float loc = accL[j][r] + biasL[r];
                    float sc  = accS[j][r] + biasS[r];
                    y[j][r] = __expf(-sc) * (y[j][r] - loc);
                }
        }
        // next ybf write safe: all ybf readers (G1) are behind B2; next G1
        // buf writes are behind next B1 (separating this G3's buf reads)
    }

    #pragma unroll
    for (int j = 0; j < 2; ++j)
        *(f32x4*)(out + (long)(blk * MTILE + (hb2 + j) * 16 + l16) * DIM
                      + dt * 16 + quad * 4) = y[j];
}

extern "C" void kernel_launch(void* const* d_in, const int* in_sizes, int n_in,
                              void* d_out, int out_size, void* d_ws, size_t ws_size,
                              hipStream_t stream) {
    const float* u   = (const float*)d_in[0];
    const float* lW0 = (const float*)d_in[1];
    const float* lb0 = (const float*)d_in[2];
    const float* lW1 = (const float*)d_in[3];
    const float* lb1 = (const float*)d_in[4];
    const float* lW2 = (const float*)d_in[5];
    const float* lb2 = (const float*)d_in[6];
    const float* sW0 = (const float*)d_in[7];
    const float* sb0 = (const float*)d_in[8];
    const float* sW1 = (const float*)d_in[9];
    const float* sb1 = (const float*)d_in[10];
    const float* sW2 = (const float*)d_in[11];
    const float* sb2 = (const float*)d_in[12];
    // d_in[13..15] = M0,M1,M2 — masks computed analytically in pack_weights

    if (ws_size < (size_t)PACK_TOT * sizeof(__bf16)) return;
    __bf16* ws = (__bf16*)d_ws;

    pack_weights<<<PACK_TOT / 8 / 256, 256, 0, stream>>>(
        lW0, lW1, lW2, sW0, sW1, sW2, ws);
    flow_kernel<<<NBLOCKS, 512, 0, stream>>>(
        u, ws, lb0, lb1, lb2, sb0, sb1, sb2, (float*)d_out);
}